// Round 8
// baseline (50.729 us; speedup 1.0000x reference)
//
#include <hip/hip_runtime.h>
#include <hip/hip_bf16.h>
#include <hip/hip_fp8.h>

// Problem constants (fixed by setup_inputs): B=4096, d=128, M=8192, C=16
#define B_ROWS 4096
#define D_K    128
#define M_ROWS 8192
#define N_TOT  12288   // B_ROWS + M_ROWS
#define NCHUNK 32      // j-chunks (grid.x of sim)
#define JFRAG  24      // 16-col fragments per chunk (384 cols)
#define NCLS   16

typedef __attribute__((ext_vector_type(8))) int   intx8;
typedef __attribute__((ext_vector_type(4))) float floatx4;

// ---------------------------------------------------------------------------
// Kernel 1: normalize rows of f / f_neg into OCP fp8-e4m3 G8[N_TOT][128].
// One wave per row; lane holds 2 floats. Block 0 zeros S/hist/out.
// ---------------------------------------------------------------------------
__global__ __launch_bounds__(256) void nrm_kernel(
    const float* __restrict__ f, const float* __restrict__ fneg,
    unsigned char* __restrict__ G8, float* __restrict__ S,
    int* __restrict__ hist, float* __restrict__ out)
{
    const int tid  = threadIdx.x;
    const int wave = tid >> 6;
    const int lane = tid & 63;
    const int row  = blockIdx.x * 4 + wave;           // grid exact: 3072*4
    if (blockIdx.x == 0) {
        #pragma unroll
        for (int k = 0; k < 8; ++k) S[tid + k * 256] = 0.f;
        if (tid < NCLS) hist[tid] = 0;
        if (tid == 0) out[0] = 0.f;
    }
    const float* src = (row < B_ROWS) ? (f + (size_t)row * D_K)
                                      : (fneg + (size_t)(row - B_ROWS) * D_K);
    float2 v = *reinterpret_cast<const float2*>(src + lane * 2);
    float ss = v.x * v.x + v.y * v.y;
    #pragma unroll
    for (int m = 1; m < 64; m <<= 1) ss += __shfl_xor(ss, m, 64);
    const float scale = 1.0f / fmaxf(sqrtf(ss), 1e-8f);   // 1/max(||x||, EPS)
    __hip_fp8_e4m3 q0(v.x * scale);
    __hip_fp8_e4m3 q1(v.y * scale);
    const unsigned short pk =
        (unsigned short)q0.__x | ((unsigned short)q1.__x << 8);
    *reinterpret_cast<unsigned short*>(G8 + (size_t)row * D_K + lane * 2) = pk;
}

// ---------------------------------------------------------------------------
// Kernel 2: per-class sums S[c][d] (f32 of fp8 values) + label histogram.
// 128 blocks (32 row-stripes x 4 d-chunks of 32 dims) x 256 thr.
// LDS partials, then global atomicAdd merge (low contention).
// ---------------------------------------------------------------------------
__global__ __launch_bounds__(256) void csum_kernel(
    const unsigned char* __restrict__ G8, const int* __restrict__ labels,
    float* __restrict__ S, int* __restrict__ hist)
{
    __shared__ float Sp[NCLS * 32];
    __shared__ int   lh[NCLS];
    const int tid    = threadIdx.x;
    const int stripe = blockIdx.x & 31;   // 128-row stripe
    const int dc     = blockIdx.x >> 5;   // 0..3 : 32-dim chunk
    #pragma unroll
    for (int k = tid; k < NCLS * 32; k += 256) Sp[k] = 0.f;
    if (tid < NCLS) lh[tid] = 0;
    __syncthreads();

    const int j0 = stripe * 128;
    if (dc == 0 && tid < 128) atomicAdd(&lh[labels[j0 + tid]], 1);

    const int d = tid & 31;
    const int w = tid >> 5;               // 0..7 row-walkers
    for (int jj = w; jj < 128; jj += 8) {
        const int j = j0 + jj;
        const int c = labels[j];
        const float v = float(reinterpret_cast<const __hip_fp8_e4m3&>(
            G8[(size_t)j * D_K + dc * 32 + d]));
        atomicAdd(&Sp[c * 32 + d], v);
    }
    __syncthreads();
    for (int k = tid; k < NCLS * 32; k += 256) {
        const int c  = k >> 5;
        const int dd = k & 31;
        atomicAdd(&S[c * D_K + dc * 32 + dd], Sp[k]);
    }
    if (dc == 0 && tid < NCLS) atomicAdd(&hist[tid], lh[tid]);
}

// ---------------------------------------------------------------------------
// Kernel 3: branch-free exp-sum GEMM via MX-FP8 K=128 — LDS-free,
// barrier-free. Grid (32, 32) x 256 thr (4 waves). Block i-tile 128 rows;
// wave owns 32i x 384j: loops 24 x 16-col B fragments loaded DIRECTLY from
// L1/L2 (G8 is 1.5MB, L2-resident; a wave's fragment load covers a
// contiguous 2KB block -> fully coalesced; the block's 4 waves share the
// same B stream -> L1 hits). Per fragment: 2 MFMAs + 8 exp-accumulates.
// acc live range = 1 fragment -> ~60 VGPR, no barriers, pure TLP.
// A/B lane->byte mappings identical, so any K-permutation cancels in G*G^T.
// C/D: col(j) = lane&15, row(i) = (lane>>4)*4 + reg (shape-determined).
// ---------------------------------------------------------------------------
__global__ __launch_bounds__(256, 4) void sim_kernel(
    const unsigned char* __restrict__ G8, float* __restrict__ part_d)
{
    const int jc   = blockIdx.x;          // 0..31
    const int it   = blockIdx.y;          // 0..31
    const int tid  = threadIdx.x;         // 0..255
    const int wave = tid >> 6;            // 0..3 : i-quarter
    const int lane = tid & 63;
    const int i0   = it * 128 + wave * 32;

    const int r16 = lane & 15;
    const int grp = lane >> 4;            // 0..3

    // resident A fragments [a]: rows i0 + a*16 + r16, bytes grp*32..+31
    const unsigned char* Abase = G8 + (size_t)(i0 + r16) * D_K + grp * 32;
    intx8 afr[2];
    #pragma unroll
    for (int a = 0; a < 2; ++a)
        afr[a] = *reinterpret_cast<const intx8*>(Abase + (size_t)a * 16 * D_K);

    float dsum[2][4];
    #pragma unroll
    for (int a = 0; a < 2; ++a)
        #pragma unroll
        for (int r = 0; r < 4; ++r) dsum[a][r] = 0.f;

    // B fragment pointer for this lane: row (j + r16), bytes grp*32..+31
    const unsigned char* Bbase =
        G8 + (size_t)(jc * (JFRAG * 16) + r16) * D_K + grp * 32;

    #pragma unroll 2
    for (int t = 0; t < JFRAG; ++t) {
        const intx8 bfr = *reinterpret_cast<const intx8*>(
            Bbase + (size_t)t * 16 * D_K);
        floatx4 acc[2];
        #pragma unroll
        for (int a = 0; a < 2; ++a)
            acc[a] = __builtin_amdgcn_mfma_scale_f32_16x16x128_f8f6f4(
                afr[a], bfr, (floatx4){0.f, 0.f, 0.f, 0.f}, 0, 0,
                0, 0x7F7F7F7F, 0, 0x7F7F7F7F);   // unity scales
        #pragma unroll
        for (int a = 0; a < 2; ++a)
            #pragma unroll
            for (int r = 0; r < 4; ++r)
                dsum[a][r] += __expf(acc[a][r]);
    }

    // 16-lane (column-group) reduce
    #pragma unroll
    for (int a = 0; a < 2; ++a)
        #pragma unroll
        for (int r = 0; r < 4; ++r) {
            #pragma unroll
            for (int m = 1; m < 16; m <<= 1)
                dsum[a][r] += __shfl_xor(dsum[a][r], m, 64);
        }
    if (r16 == 0) {
        #pragma unroll
        for (int a = 0; a < 2; ++a)
            #pragma unroll
            for (int r = 0; r < 4; ++r)
                part_d[(size_t)(i0 + a * 16 + grp * 4 + r) * NCHUNK + jc] =
                    dsum[a][r];
    }
}

// ---------------------------------------------------------------------------
// Kernel 4: finalize. 128 blocks x 4 waves; each wave owns 8 rows.
// Per row: denom = sum(part) - exp(selfdot); psum = <g_i, S[lab]> - selfdot;
// loss = log(denom) - psum/npos. Block reduce -> atomicAdd(out, mean part).
// ---------------------------------------------------------------------------
__global__ __launch_bounds__(256) void fin_kernel(
    const unsigned char* __restrict__ G8, const float* __restrict__ part_d,
    const float* __restrict__ S, const int* __restrict__ labels,
    const int* __restrict__ hist, float* __restrict__ out)
{
    const int tid  = threadIdx.x;
    const int wave = tid >> 6;
    const int lane = tid & 63;

    float lsum = 0.f;
    #pragma unroll 2
    for (int rr = 0; rr < 8; ++rr) {
        const int i   = (blockIdx.x * 4 + wave) * 8 + rr;
        const int lab = labels[i];
        float pd = (lane < NCHUNK) ? part_d[(size_t)i * NCHUNK + lane] : 0.f;
        const unsigned char* gr = G8 + (size_t)i * D_K + lane * 2;
        const float f0 = float(reinterpret_cast<const __hip_fp8_e4m3&>(gr[0]));
        const float f1 = float(reinterpret_cast<const __hip_fp8_e4m3&>(gr[1]));
        float2 sv = *reinterpret_cast<const float2*>(S + lab * D_K + lane * 2);
        float self = f0 * f0 + f1 * f1;
        float sp   = f0 * sv.x + f1 * sv.y;
        #pragma unroll
        for (int m = 1; m < 64; m <<= 1) {
            pd   += __shfl_xor(pd, m, 64);
            self += __shfl_xor(self, m, 64);
            sp   += __shfl_xor(sp, m, 64);
        }
        if (lane == 0) {
            const float npos  = (float)(hist[lab] - 1);
            const float denom = pd - __expf(self);
            lsum += __logf(denom) - (sp - self) / npos;
        }
    }
    __shared__ float w4[4];
    if (lane == 0) w4[wave] = lsum;
    __syncthreads();
    if (tid == 0)
        atomicAdd(out, (w4[0] + w4[1] + w4[2] + w4[3]) * (1.0f / (float)B_ROWS));
}

// ---------------------------------------------------------------------------
extern "C" void kernel_launch(void* const* d_in, const int* in_sizes, int n_in,
                              void* d_out, int out_size, void* d_ws, size_t ws_size,
                              hipStream_t stream) {
    const float* f      = (const float*)d_in[0];
    const float* fneg   = (const float*)d_in[1];
    const int*   labels = (const int*)d_in[2];
    float*       out    = (float*)d_out;

    char* ws = (char*)d_ws;
    // Workspace layout (bytes):
    //   G8     : 12288*128   = 1,572,864
    //   part_d : 4096*32*4   =   524,288
    //   S      : 16*128*4    =     8,192
    //   hist   : 16*4
    unsigned char* G8     = (unsigned char*)(ws);
    float*         part_d = (float*)(ws + 1572864);
    float*         S      = (float*)(ws + 1572864 + 524288);
    int*           hist   = (int*)(ws + 1572864 + 524288 + 8192);

    nrm_kernel<<<N_TOT / 4, 256, 0, stream>>>(f, fneg, G8, S, hist, out);
    csum_kernel<<<128, 256, 0, stream>>>(G8, labels, S, hist);

    dim3 gridS(NCHUNK, 32);   // (32, 32) = 1024 blocks, 4/CU
    sim_kernel<<<gridS, 256, 0, stream>>>(G8, part_d);

    fin_kernel<<<128, 256, 0, stream>>>(G8, part_d, S, labels, hist, out);
}

// Round 10
// 39.700 us; speedup vs baseline: 1.2778x; 1.2778x over previous
//
#include <hip/hip_runtime.h>
#include <hip/hip_bf16.h>
#include <hip/hip_fp8.h>

// Problem constants (fixed by setup_inputs): B=4096, d=128, M=8192, C=16
#define B_ROWS 4096
#define D_K    128
#define M_ROWS 8192
#define N_TOT  12288   // B_ROWS + M_ROWS
#define NCHUNK 96      // j-chunks (grid.x of sim), 128 cols each
#define JCOLS  128     // cols per chunk  -- NCHUNK*JCOLS MUST equal N_TOT
#define JFRAG  8       // 16-col fragments per chunk
#define NCLS   16

typedef __attribute__((ext_vector_type(4))) int   intx4;
typedef __attribute__((ext_vector_type(8))) int   intx8;
typedef __attribute__((ext_vector_type(4))) float floatx4;

// ---------------------------------------------------------------------------
// Kernel 1: normalize rows of f / f_neg into OCP fp8-e4m3 G8[N_TOT][128].
// One wave per row; lane holds 2 floats. Block 0 zeros S/hist/out.
// ---------------------------------------------------------------------------
__global__ __launch_bounds__(256) void nrm_kernel(
    const float* __restrict__ f, const float* __restrict__ fneg,
    unsigned char* __restrict__ G8, float* __restrict__ S,
    int* __restrict__ hist, float* __restrict__ out)
{
    const int tid  = threadIdx.x;
    const int wave = tid >> 6;
    const int lane = tid & 63;
    const int row  = blockIdx.x * 4 + wave;           // grid exact: 3072*4
    if (blockIdx.x == 0) {
        #pragma unroll
        for (int k = 0; k < 8; ++k) S[tid + k * 256] = 0.f;
        if (tid < NCLS) hist[tid] = 0;
        if (tid == 0) out[0] = 0.f;
    }
    const float* src = (row < B_ROWS) ? (f + (size_t)row * D_K)
                                      : (fneg + (size_t)(row - B_ROWS) * D_K);
    float2 v = *reinterpret_cast<const float2*>(src + lane * 2);
    float ss = v.x * v.x + v.y * v.y;
    #pragma unroll
    for (int m = 1; m < 64; m <<= 1) ss += __shfl_xor(ss, m, 64);
    const float scale = 1.0f / fmaxf(sqrtf(ss), 1e-8f);   // 1/max(||x||, EPS)
    __hip_fp8_e4m3 q0(v.x * scale);
    __hip_fp8_e4m3 q1(v.y * scale);
    const unsigned short pk =
        (unsigned short)q0.__x | ((unsigned short)q1.__x << 8);
    *reinterpret_cast<unsigned short*>(G8 + (size_t)row * D_K + lane * 2) = pk;
}

// ---------------------------------------------------------------------------
// Kernel 2: per-class sums S[c][d] (f32 of fp8 values) + label histogram.
// 128 blocks (32 row-stripes x 4 d-chunks of 32 dims) x 256 thr.
// LDS partials, then global atomicAdd merge (low contention).
// ---------------------------------------------------------------------------
__global__ __launch_bounds__(256) void csum_kernel(
    const unsigned char* __restrict__ G8, const int* __restrict__ labels,
    float* __restrict__ S, int* __restrict__ hist)
{
    __shared__ float Sp[NCLS * 32];
    __shared__ int   lh[NCLS];
    const int tid    = threadIdx.x;
    const int stripe = blockIdx.x & 31;   // 128-row stripe
    const int dc     = blockIdx.x >> 5;   // 0..3 : 32-dim chunk
    #pragma unroll
    for (int k = tid; k < NCLS * 32; k += 256) Sp[k] = 0.f;
    if (tid < NCLS) lh[tid] = 0;
    __syncthreads();

    const int j0 = stripe * 128;
    if (dc == 0 && tid < 128) atomicAdd(&lh[labels[j0 + tid]], 1);

    const int d = tid & 31;
    const int w = tid >> 5;               // 0..7 row-walkers
    for (int jj = w; jj < 128; jj += 8) {
        const int j = j0 + jj;
        const int c = labels[j];
        const float v = float(reinterpret_cast<const __hip_fp8_e4m3&>(
            G8[(size_t)j * D_K + dc * 32 + d]));
        atomicAdd(&Sp[c * 32 + d], v);
    }
    __syncthreads();
    for (int k = tid; k < NCLS * 32; k += 256) {
        const int c  = k >> 5;
        const int dd = k & 31;
        atomicAdd(&S[c * D_K + dc * 32 + dd], Sp[k]);
    }
    if (dc == 0 && tid < NCLS) atomicAdd(&hist[tid], lh[tid]);
}

// ---------------------------------------------------------------------------
// Kernel 3: branch-free exp-sum GEMM via MX-FP8 K=128, SINGLE-BARRIER.
// Grid (96, 32) = 3072 blocks x 256 thr (4 waves) = 12 blocks/CU dispatched
// (~10 co-resident by 16KB LDS). COVERAGE: NCHUNK*JCOLS = 96*128 = 12288 =
// N_TOT (R9 bug: 64*128 = 8192 missed a third of the denominator).
// Block: i-tile 128 rows, j-chunk 128 cols. B chunk (16KB) staged to LDS in
// 4 linear rounds (16B/thr, source granule pre-swizzled gran = slot^(row&7),
// R5-R8 verified), then ONE __syncthreads, then 8 fragments with zero
// further sync (pure lgkmcnt dataflow). Wave owns 32i x 128j: per fragment
// 2 MFMAs (mfma_scale_f32_16x16x128_f8f6f4, unity scales) + 8 exp-adds.
// ~55 VGPR; co-resident blocks hide each other's staging + barrier.
// A/B lane->byte mappings identical, so any K-permutation cancels in G*G^T.
// C/D: col(j) = lane&15, row(i) = (lane>>4)*4 + reg (shape-determined).
// ---------------------------------------------------------------------------
__global__ __launch_bounds__(256, 6) void sim_kernel(
    const unsigned char* __restrict__ G8, float* __restrict__ part_d)
{
    __shared__ unsigned char Bs[JCOLS * D_K];   // 16KB, single buffer

    const int jc   = blockIdx.x;          // 0..95
    const int it   = blockIdx.y;          // 0..31
    const int tid  = threadIdx.x;         // 0..255
    const int wave = tid >> 6;            // 0..3 : i-quarter
    const int lane = tid & 63;
    const int i0   = it * 128 + wave * 32;

    const int r16 = lane & 15;
    const int grp = lane >> 4;            // 0..3

    // stage B chunk: 4 rounds x 256 thr x 16B. LDS linear byte
    // p = s*4096 + tid*16 -> row = s*32 + tid/8, slot = tid&7;
    // source granule pre-swizzled: gran = slot ^ (row&7).
    {
        const unsigned char* src = G8 + (size_t)jc * JCOLS * D_K;
        #pragma unroll
        for (int s = 0; s < 4; ++s) {
            const int row  = s * 32 + (tid >> 3);
            const int gran = (tid & 7) ^ (row & 7);
            const intx4 v = *reinterpret_cast<const intx4*>(
                src + row * D_K + gran * 16);
            *reinterpret_cast<intx4*>(&Bs[0] + s * 4096 + tid * 16) = v;
        }
    }

    // resident A fragments [a]: rows i0 + a*16 + r16, bytes grp*32..+31
    const unsigned char* Abase = G8 + (size_t)(i0 + r16) * D_K + grp * 32;
    intx8 afr[2];
    #pragma unroll
    for (int a = 0; a < 2; ++a)
        afr[a] = *reinterpret_cast<const intx8*>(Abase + (size_t)a * 16 * D_K);

    float dsum[2][4];
    #pragma unroll
    for (int a = 0; a < 2; ++a)
        #pragma unroll
        for (int r = 0; r < 4; ++r) dsum[a][r] = 0.f;

    __syncthreads();   // the ONLY barrier

    #pragma unroll
    for (int b = 0; b < JFRAG; ++b) {
        const int jloc = b * 16 + r16;
        const int sw   = jloc & 7;
        const intx4 lo = *reinterpret_cast<const intx4*>(
            &Bs[0] + jloc * D_K + ((2 * grp)     ^ sw) * 16);
        const intx4 hi = *reinterpret_cast<const intx4*>(
            &Bs[0] + jloc * D_K + ((2 * grp + 1) ^ sw) * 16);
        intx8 bfr;
        #pragma unroll
        for (int e = 0; e < 4; ++e) { bfr[e] = lo[e]; bfr[e + 4] = hi[e]; }
        floatx4 acc[2];
        #pragma unroll
        for (int a = 0; a < 2; ++a)
            acc[a] = __builtin_amdgcn_mfma_scale_f32_16x16x128_f8f6f4(
                afr[a], bfr, (floatx4){0.f, 0.f, 0.f, 0.f}, 0, 0,
                0, 0x7F7F7F7F, 0, 0x7F7F7F7F);   // unity scales
        #pragma unroll
        for (int a = 0; a < 2; ++a)
            #pragma unroll
            for (int r = 0; r < 4; ++r)
                dsum[a][r] += __expf(acc[a][r]);
    }

    // 16-lane (column-group) reduce
    #pragma unroll
    for (int a = 0; a < 2; ++a)
        #pragma unroll
        for (int r = 0; r < 4; ++r) {
            #pragma unroll
            for (int m = 1; m < 16; m <<= 1)
                dsum[a][r] += __shfl_xor(dsum[a][r], m, 64);
        }
    if (r16 == 0) {
        #pragma unroll
        for (int a = 0; a < 2; ++a)
            #pragma unroll
            for (int r = 0; r < 4; ++r)
                part_d[(size_t)(i0 + a * 16 + grp * 4 + r) * NCHUNK + jc] =
                    dsum[a][r];
    }
}

// ---------------------------------------------------------------------------
// Kernel 4: finalize. 128 blocks x 4 waves; each wave owns 8 rows.
// Per row: denom = sum of 96 partials - exp(selfdot);
// psum = <g_i, S[lab]> - selfdot; loss = log(denom) - psum/npos.
// Block reduce -> atomicAdd(out, mean part).
// ---------------------------------------------------------------------------
__global__ __launch_bounds__(256) void fin_kernel(
    const unsigned char* __restrict__ G8, const float* __restrict__ part_d,
    const float* __restrict__ S, const int* __restrict__ labels,
    const int* __restrict__ hist, float* __restrict__ out)
{
    const int tid  = threadIdx.x;
    const int wave = tid >> 6;
    const int lane = tid & 63;

    float lsum = 0.f;
    #pragma unroll 2
    for (int rr = 0; rr < 8; ++rr) {
        const int i   = (blockIdx.x * 4 + wave) * 8 + rr;
        const int lab = labels[i];
        // 96 slices: lane reads slice lane, lanes 0..31 also read slice 64+lane
        float pd = part_d[(size_t)i * NCHUNK + lane];
        if (lane < NCHUNK - 64)
            pd += part_d[(size_t)i * NCHUNK + 64 + lane];
        const unsigned char* gr = G8 + (size_t)i * D_K + lane * 2;
        const float f0 = float(reinterpret_cast<const __hip_fp8_e4m3&>(gr[0]));
        const float f1 = float(reinterpret_cast<const __hip_fp8_e4m3&>(gr[1]));
        float2 sv = *reinterpret_cast<const float2*>(S + lab * D_K + lane * 2);
        float self = f0 * f0 + f1 * f1;
        float sp   = f0 * sv.x + f1 * sv.y;
        #pragma unroll
        for (int m = 1; m < 64; m <<= 1) {
            pd   += __shfl_xor(pd, m, 64);
            self += __shfl_xor(self, m, 64);
            sp   += __shfl_xor(sp, m, 64);
        }
        if (lane == 0) {
            const float npos  = (float)(hist[lab] - 1);
            const float denom = pd - __expf(self);
            lsum += __logf(denom) - (sp - self) / npos;
        }
    }
    __shared__ float w4[4];
    if (lane == 0) w4[wave] = lsum;
    __syncthreads();
    if (tid == 0)
        atomicAdd(out, (w4[0] + w4[1] + w4[2] + w4[3]) * (1.0f / (float)B_ROWS));
}

// ---------------------------------------------------------------------------
extern "C" void kernel_launch(void* const* d_in, const int* in_sizes, int n_in,
                              void* d_out, int out_size, void* d_ws, size_t ws_size,
                              hipStream_t stream) {
    const float* f      = (const float*)d_in[0];
    const float* fneg   = (const float*)d_in[1];
    const int*   labels = (const int*)d_in[2];
    float*       out    = (float*)d_out;

    char* ws = (char*)d_ws;
    // Workspace layout (bytes):
    //   G8     : 12288*128   = 1,572,864
    //   part_d : 4096*96*4   = 1,572,864
    //   S      : 16*128*4    =     8,192
    //   hist   : 16*4
    unsigned char* G8     = (unsigned char*)(ws);
    float*         part_d = (float*)(ws + 1572864);
    float*         S      = (float*)(ws + 1572864 + 1572864);
    int*           hist   = (int*)(ws + 1572864 + 1572864 + 8192);

    nrm_kernel<<<N_TOT / 4, 256, 0, stream>>>(f, fneg, G8, S, hist, out);
    csum_kernel<<<128, 256, 0, stream>>>(G8, labels, S, hist);

    dim3 gridS(NCHUNK, 32);   // (96, 32) = 3072 blocks; 96*128 = 12288 = N_TOT
    sim_kernel<<<gridS, 256, 0, stream>>>(G8, part_d);

    fin_kernel<<<128, 256, 0, stream>>>(G8, part_d, S, labels, hist, out);
}